// Round 14
// baseline (297.483 us; speedup 1.0000x reference)
//
#include <hip/hip_runtime.h>
#include <math.h>

#define CHUNK 16384
#define BSTRIDE 17408   // per-bucket edge capacity: mean 16327 + >8 sigma

// ================= single-pass bucket scatter (packed u32, fixed-stride buckets) =================
// bucket b = dst >> 9 (512 nodes); edge packed as (src << 9) | (dst & 511)

__global__ void __launch_bounds__(256) k_bscatter1p(const int* __restrict__ src,
                                                    const int* __restrict__ dst, int e,
                                                    int* __restrict__ bcur,
                                                    unsigned* __restrict__ eu) {
    __shared__ unsigned short rank[CHUNK];
    __shared__ int cnt[256];
    __shared__ int base[256];
    int t = threadIdx.x;
    int c0 = blockIdx.x * CHUNK;
    cnt[t] = 0;
    __syncthreads();
#pragma unroll
    for (int k = 0; k < CHUNK / 256; k++) {
        int i = c0 + k * 256 + t;
        if (i < e) {
            int b = dst[i] >> 9;
            rank[k * 256 + t] = (unsigned short)atomicAdd(&cnt[b], 1);
        }
    }
    __syncthreads();
    int cb = cnt[t];
    base[t] = cb ? atomicAdd(&bcur[t], cb) : 0;
    __syncthreads();
#pragma unroll
    for (int k = 0; k < CHUNK / 256; k++) {
        int i = c0 + k * 256 + t;
        if (i < e) {
            int d = dst[i];
            int b = d >> 9;
            eu[(size_t)b * BSTRIDE + base[b] + rank[k * 256 + t]] =
                ((unsigned)src[i] << 9) | (unsigned)(d & 511);
        }
    }
}

// per bucket: histogram+scan -> deg/off/dinv, xs = x*dinv, scatter csr (two eu passes, LDS atomics)
__global__ void __launch_bounds__(256) k_bprep(const unsigned* __restrict__ eu,
                                               const int* __restrict__ bcur,
                                               const float* __restrict__ x,
                                               int* __restrict__ deg, int* __restrict__ off,
                                               float* __restrict__ dinv, float* __restrict__ xs,
                                               int* __restrict__ csr, int n) {
    __shared__ int h[512];
    __shared__ int offL[512];
    __shared__ int curL[512];
    __shared__ float sdv[512];
    int t = threadIdx.x, b = blockIdx.x;
    h[t] = 0; h[t + 256] = 0;
    curL[t] = 0; curL[t + 256] = 0;
    __syncthreads();
    int s0 = b * BSTRIDE;
    int s1 = s0 + bcur[b];
    for (int i = s0 + t; i < s1; i += 256)
        atomicAdd(&h[eu[i] & 511u], 1);
    __syncthreads();
    int o0 = h[t], o1 = h[t + 256];
    for (int d = 1; d < 512; d <<= 1) {
        int a0 = (t >= d) ? h[t - d] : 0;
        int a1 = (t + 256 >= d) ? h[t + 256 - d] : 0;
        __syncthreads();
        h[t] += a0; h[t + 256] += a1;
        __syncthreads();
    }
    int nbase = b << 9;
    int n0 = nbase + t, n1 = nbase + t + 256;
    int ofA = s0 + h[t] - o0, ofB = s0 + h[t + 256] - o1;
    offL[t] = ofA; offL[t + 256] = ofB;
    if (n0 < n) {
        float dv = rsqrtf((float)(o0 + 1));
        deg[n0] = o0; off[n0] = ofA; dinv[n0] = dv; sdv[t] = dv;
    }
    if (n1 < n) {
        float dv = rsqrtf((float)(o1 + 1));
        deg[n1] = o1; off[n1] = ofB; dinv[n1] = dv; sdv[t + 256] = dv;
    }
    __syncthreads();
    int limit = (n - nbase) * 8;
    if (limit > 4096) limit = 4096;
    for (int idx = t; idx < limit; idx += 256)
        xs[(size_t)nbase * 8 + idx] = x[(size_t)nbase * 8 + idx] * sdv[idx >> 3];
    for (int i = s0 + t; i < s1; i += 256) {
        unsigned p = eu[i];
        int local = (int)(p & 511u);
        int r = atomicAdd(&curL[local], 1);
        csr[offL[local] + r] = (int)(p >> 9);
    }
}

// ================= conv1 gather + W1 GEMM fused =================

__global__ void __launch_bounds__(256) k_c8h1(const float* __restrict__ xs,
                                              const int* __restrict__ csr,
                                              const int* __restrict__ off,
                                              const int* __restrict__ deg,
                                              const float* __restrict__ W1,
                                              const float* __restrict__ b1,
                                              const float* __restrict__ dinv,
                                              float* __restrict__ H1s, int n) {
    __shared__ float w1s[512];
    __shared__ float b1s[64];
    int t = threadIdx.x;
    w1s[t] = W1[t];
    w1s[t + 256] = W1[t + 256];
    if (t < 64) b1s[t] = b1[t];
    __syncthreads();
    int g = (blockIdx.x * 256 + t) >> 3;
    int lane = t & 7;
    if (g >= n) return;
    int base = off[g], cnt = deg[g];
    float acc = xs[g * 8 + lane];
    int e = 0;
    for (; e + 4 <= cnt; e += 4) {
        int s0 = csr[base + e];
        int s1 = csr[base + e + 1];
        int s2 = csr[base + e + 2];
        int s3 = csr[base + e + 3];
        acc += xs[s0 * 8 + lane];
        acc += xs[s1 * 8 + lane];
        acc += xs[s2 * 8 + lane];
        acc += xs[s3 * 8 + lane];
    }
    for (; e < cnt; e++) acc += xs[csr[base + e] * 8 + lane];
    float dv = dinv[g];
    float o[8];
#pragma unroll
    for (int j = 0; j < 8; j++) o[j] = 0.f;
#pragma unroll
    for (int k = 0; k < 8; k++) {
        float av = __shfl(acc, (t & 56) | k);
#pragma unroll
        for (int j = 0; j < 8; j++) o[j] += av * w1s[k * 64 + lane * 8 + j];
    }
    float4 r0, r1;
    r0.x = fmaxf(dv * o[0] + b1s[lane * 8 + 0], 0.f) * dv;
    r0.y = fmaxf(dv * o[1] + b1s[lane * 8 + 1], 0.f) * dv;
    r0.z = fmaxf(dv * o[2] + b1s[lane * 8 + 2], 0.f) * dv;
    r0.w = fmaxf(dv * o[3] + b1s[lane * 8 + 3], 0.f) * dv;
    r1.x = fmaxf(dv * o[4] + b1s[lane * 8 + 4], 0.f) * dv;
    r1.y = fmaxf(dv * o[5] + b1s[lane * 8 + 5], 0.f) * dv;
    r1.z = fmaxf(dv * o[6] + b1s[lane * 8 + 6], 0.f) * dv;
    r1.w = fmaxf(dv * o[7] + b1s[lane * 8 + 7], 0.f) * dv;
    *(float4*)&H1s[(size_t)g * 64 + lane * 8]     = r0;
    *(float4*)&H1s[(size_t)g * 64 + lane * 8 + 4] = r1;
}

// ================= conv2 aggregate: one wave per dst, 16 rows in flight =================

__global__ void __launch_bounds__(256) k_conv64(const float* __restrict__ G,
                                                const int* __restrict__ csr,
                                                const int* __restrict__ off,
                                                const int* __restrict__ deg,
                                                float* __restrict__ agg2, int n) {
    int d = (blockIdx.x * 256 + threadIdx.x) >> 6;
    int j = threadIdx.x & 63;
    if (d >= n) return;
    int du = __builtin_amdgcn_readfirstlane(d);
    int base = off[du], cnt = deg[du];
    const float* Gj = G + j;
    float acc = Gj[(size_t)du * 64];
    int e = 0;
    for (; e + 16 <= cnt; e += 16) {
        int s[16];
#pragma unroll
        for (int u = 0; u < 16; u++) s[u] = csr[base + e + u];
        float v[16];
#pragma unroll
        for (int u = 0; u < 16; u++) v[u] = Gj[(size_t)s[u] * 64];
#pragma unroll
        for (int u = 0; u < 16; u++) acc += v[u];
    }
    for (; e + 8 <= cnt; e += 8) {
        int s[8];
#pragma unroll
        for (int u = 0; u < 8; u++) s[u] = csr[base + e + u];
        float v[8];
#pragma unroll
        for (int u = 0; u < 8; u++) v[u] = Gj[(size_t)s[u] * 64];
#pragma unroll
        for (int u = 0; u < 8; u++) acc += v[u];
    }
    for (; e < cnt; e++) acc += Gj[(size_t)csr[base + e] * 64];
    agg2[(size_t)d * 64 + j] = acc;
}

// ================= dgt[w][j] = b1[j] + Hfin(dsi[w])@M1b + Hfin(n-1)@M1c (from agg2) =================

__global__ void k_dgt2(const float* __restrict__ agg2, const int* __restrict__ dsi,
                       const float* __restrict__ dinv,
                       const float* __restrict__ W2, const float* __restrict__ b2,
                       const float* __restrict__ M1, const float* __restrict__ b1,
                       float* __restrict__ dgt, int n, int nd) {
    int w = (blockIdx.x * blockDim.x + threadIdx.x) >> 6;
    int lane = threadIdx.x & 63;
    if (w >= nd) return;
    int nodeD = dsi[w];
    float avD = agg2[(size_t)nodeD * 64 + lane];
    float dvD = dinv[nodeD];
    float avG = agg2[(size_t)(n - 1) * 64 + lane];
    float dvG = dinv[n - 1];
    float sD = 0.f, sG = 0.f;
#pragma unroll
    for (int k = 0; k < 64; k++) {
        float wv = W2[k * 64 + lane];
        sD += __shfl(avD, k) * wv;
        sG += __shfl(avG, k) * wv;
    }
    float bb = b2[lane];
    float hd = fmaxf(dvD * sD + bb, 0.f);
    float hg = fmaxf(dvG * sG + bb, 0.f);
    float z = b1[lane];
#pragma unroll
    for (int k = 0; k < 64; k++) z += __shfl(hd, k) * M1[(64 + k) * 64 + lane];
#pragma unroll
    for (int k = 0; k < 64; k++) z += __shfl(hg, k) * M1[(128 + k) * 64 + lane];
    dgt[w * 64 + lane] = z;
}

// ================= fused: Hfin=relu(dinv*(agg2@W2)+b2) -> MLP -> scores =================

__global__ void __launch_bounds__(256) k_gm(const float* __restrict__ agg2,
                                            const float* __restrict__ dinv,
                                            const float* __restrict__ W2,
                                            const float* __restrict__ b2,
                                            const float* __restrict__ dgt,
                                            const float* __restrict__ x,
                                            const float* __restrict__ M1,
                                            const float* __restrict__ M2,
                                            const float* __restrict__ mb2,
                                            const float* __restrict__ M3,
                                            const float* __restrict__ mb3,
                                            float* __restrict__ scores, int n, int nd) {
    __shared__ float hs[128 * 65];
    __shared__ float ws[64 * 64];
    int tid = threadIdx.x;
    int base = blockIdx.x * 128;
#pragma unroll
    for (int m = 0; m < 4; m++) {
        int i = (m * 256 + tid) * 4;
        *(float4*)&ws[i] = *(const float4*)&W2[i];
    }
#pragma unroll
    for (int m = 0; m < 8; m++) {
        int idx = (m * 256 + tid) * 4;
        int node = idx >> 6, k = idx & 63;
        float4 v = *(const float4*)&agg2[(size_t)(base + node) * 64 + k];
        hs[node * 65 + k]     = v.x;
        hs[node * 65 + k + 1] = v.y;
        hs[node * 65 + k + 2] = v.z;
        hs[node * 65 + k + 3] = v.w;
    }
    __syncthreads();
    int jg = tid & 7, ng = tid >> 3;
    int j0 = jg * 8, n0 = ng * 4;
    float acc[4][8];
#pragma unroll
    for (int i = 0; i < 4; i++)
#pragma unroll
        for (int j = 0; j < 8; j++) acc[i][j] = 0.f;
#pragma unroll 4
    for (int k = 0; k < 64; k++) {
        float av[4];
#pragma unroll
        for (int i = 0; i < 4; i++) av[i] = hs[(n0 + i) * 65 + k];
        float bv[8];
        *(float4*)&bv[0] = *(float4*)&ws[k * 64 + j0];
        *(float4*)&bv[4] = *(float4*)&ws[k * 64 + j0 + 4];
#pragma unroll
        for (int i = 0; i < 4; i++)
#pragma unroll
            for (int j = 0; j < 8; j++) acc[i][j] += av[i] * bv[j];
    }
    __syncthreads();
    float b2v[8];
    *(float4*)&b2v[0] = *(const float4*)&b2[j0];
    *(float4*)&b2v[4] = *(const float4*)&b2[j0 + 4];
#pragma unroll
    for (int i = 0; i < 4; i++) {
        int node = base + n0 + i;
        float dv = (node < n) ? dinv[node] : 0.f;
#pragma unroll
        for (int j = 0; j < 8; j++)
            hs[(n0 + i) * 65 + j0 + j] = fmaxf(acc[i][j] * dv + b2v[j], 0.f);
    }
#pragma unroll
    for (int m = 0; m < 4; m++) {
        int i = (m * 256 + tid) * 4;
        *(float4*)&ws[i] = *(const float4*)&M1[i];
    }
    __syncthreads();
#pragma unroll
    for (int i = 0; i < 4; i++)
#pragma unroll
        for (int j = 0; j < 8; j++) acc[i][j] = 0.f;
#pragma unroll 4
    for (int k = 0; k < 64; k++) {
        float av[4];
#pragma unroll
        for (int i = 0; i < 4; i++) av[i] = hs[(n0 + i) * 65 + k];
        float bv[8];
        *(float4*)&bv[0] = *(float4*)&ws[k * 64 + j0];
        *(float4*)&bv[4] = *(float4*)&ws[k * 64 + j0 + 4];
#pragma unroll
        for (int i = 0; i < 4; i++)
#pragma unroll
            for (int j = 0; j < 8; j++) acc[i][j] += av[i] * bv[j];
    }
    __syncthreads();
#pragma unroll
    for (int i = 0; i < 4; i++) {
        int node = base + n0 + i;
        int dago = (node + 1) / 100;
        if (dago >= nd) dago = nd - 1;
        float dv[8];
        *(float4*)&dv[0] = *(const float4*)&dgt[dago * 64 + j0];
        *(float4*)&dv[4] = *(const float4*)&dgt[dago * 64 + j0 + 4];
#pragma unroll
        for (int j = 0; j < 8; j++)
            hs[(n0 + i) * 65 + j0 + j] = fmaxf(acc[i][j] + dv[j], 0.f);
    }
#pragma unroll
    for (int m = 0; m < 4; m++) {
        int i = (m * 256 + tid) * 4;
        *(float4*)&ws[i] = *(const float4*)&M2[i];
    }
    __syncthreads();
    float acc2[4][8];
#pragma unroll
    for (int i = 0; i < 4; i++)
#pragma unroll
        for (int j = 0; j < 8; j++) acc2[i][j] = 0.f;
#pragma unroll 4
    for (int k = 0; k < 64; k++) {
        float av[4];
#pragma unroll
        for (int i = 0; i < 4; i++) av[i] = hs[(n0 + i) * 65 + k];
        float bv[8];
        *(float4*)&bv[0] = *(float4*)&ws[k * 64 + j0];
        *(float4*)&bv[4] = *(float4*)&ws[k * 64 + j0 + 4];
#pragma unroll
        for (int i = 0; i < 4; i++)
#pragma unroll
            for (int j = 0; j < 8; j++) acc2[i][j] += av[i] * bv[j];
    }
    float mb2v[8], m3v[8];
    *(float4*)&mb2v[0] = *(const float4*)&mb2[j0];
    *(float4*)&mb2v[4] = *(const float4*)&mb2[j0 + 4];
    *(float4*)&m3v[0] = *(const float4*)&M3[j0];
    *(float4*)&m3v[4] = *(const float4*)&M3[j0 + 4];
    float b3 = mb3[0];
#pragma unroll
    for (int i = 0; i < 4; i++) {
        float p = 0.f;
#pragma unroll
        for (int j = 0; j < 8; j++) {
            float z2 = fmaxf(acc2[i][j] + mb2v[j], 0.f);
            p += z2 * m3v[j];
        }
        p += __shfl_xor(p, 1);
        p += __shfl_xor(p, 2);
        p += __shfl_xor(p, 4);
        if (jg == 0) {
            int node = base + n0 + i;
            if (node < n - 1) {
                float flag = x[(size_t)node * 8 + 7];
                bool summary = ((node % 100) == 99);
                scores[node] = (flag == 1.0f && !summary) ? (p + b3) : -INFINITY;
            }
        }
    }
}

// ================= fused online max/argmax/exp-sum reduction =================

__global__ void k_red_ms(const float* __restrict__ scores, int n,
                         float* __restrict__ pm, float* __restrict__ ps,
                         int* __restrict__ pidx) {
    __shared__ float sm[256];
    __shared__ float ss[256];
    __shared__ int si[256];
    float m = -INFINITY, s = 0.f;
    int bi = 0x7fffffff;
    for (int i = blockIdx.x * 256 + threadIdx.x; i < n; i += gridDim.x * 256) {
        float v = scores[i];
        if (v > m) {
            s = s * expf(m - v) + 1.f;
            m = v;
            bi = i;
        } else if (v != -INFINITY) {
            s += expf(v - m);
        }
    }
    sm[threadIdx.x] = m; ss[threadIdx.x] = s; si[threadIdx.x] = bi;
    __syncthreads();
    for (int o = 128; o; o >>= 1) {
        if (threadIdx.x < o) {
            float m2 = sm[threadIdx.x + o], s2 = ss[threadIdx.x + o];
            int i2 = si[threadIdx.x + o];
            float m1 = sm[threadIdx.x], s1 = ss[threadIdx.x];
            int i1 = si[threadIdx.x];
            float M = fmaxf(m1, m2);
            float S = ((m1 == -INFINITY) ? 0.f : s1 * expf(m1 - M)) +
                      ((m2 == -INFINITY) ? 0.f : s2 * expf(m2 - M));
            int I;
            if (m2 > m1 || (m2 == m1 && i2 < i1)) I = i2; else I = i1;
            sm[threadIdx.x] = M; ss[threadIdx.x] = S; si[threadIdx.x] = I;
        }
        __syncthreads();
    }
    if (threadIdx.x == 0) { pm[blockIdx.x] = sm[0]; ps[blockIdx.x] = ss[0]; pidx[blockIdx.x] = si[0]; }
}

// combine (replicated per block, deterministic) + write probs
__global__ void k_probs(const float* __restrict__ scores,
                        const float* __restrict__ pm, const float* __restrict__ ps,
                        const int* __restrict__ pidx, int nb,
                        float* __restrict__ out, int n) {
    __shared__ float sm[256];
    __shared__ float ss[256];
    __shared__ int si[256];
    int t = threadIdx.x;
    sm[t] = (t < nb) ? pm[t] : -INFINITY;
    ss[t] = (t < nb) ? ps[t] : 0.f;
    si[t] = (t < nb) ? pidx[t] : 0x7fffffff;
    __syncthreads();
    for (int o = 128; o; o >>= 1) {
        if (t < o) {
            float m2 = sm[t + o], s2 = ss[t + o];
            int i2 = si[t + o];
            float m1 = sm[t], s1 = ss[t];
            int i1 = si[t];
            float M = fmaxf(m1, m2);
            float S = ((m1 == -INFINITY) ? 0.f : s1 * expf(m1 - M)) +
                      ((m2 == -INFINITY) ? 0.f : s2 * expf(m2 - M));
            int I;
            if (m2 > m1 || (m2 == m1 && i2 < i1)) I = i2; else I = i1;
            sm[t] = M; ss[t] = S; si[t] = I;
        }
        __syncthreads();
    }
    float m = sm[0], s = ss[0];
    int i = blockIdx.x * 256 + t;
    if (i < n) out[i] = expf(scores[i] - m) / s;
    if (i == 0) out[n] = (float)si[0];
}

// ================= host =================

extern "C" void kernel_launch(void* const* d_in, const int* in_sizes, int n_in,
                              void* d_out, int out_size, void* d_ws, size_t ws_size,
                              hipStream_t stream) {
    const float* x   = (const float*)d_in[0];
    const int*   ei  = (const int*)d_in[1];
    const int*   dsi = (const int*)d_in[2];
    const float* W1  = (const float*)d_in[3];
    const float* b1  = (const float*)d_in[4];
    const float* W2  = (const float*)d_in[5];
    const float* b2  = (const float*)d_in[6];
    const float* M1  = (const float*)d_in[7];
    const float* mb1 = (const float*)d_in[8];  (void)mb1;
    const float* M2  = (const float*)d_in[9];
    const float* mb2 = (const float*)d_in[10];
    const float* M3  = (const float*)d_in[11];
    const float* mb3 = (const float*)d_in[12];

    int N  = in_sizes[0] / 8;    // 100001
    int E  = in_sizes[1] / 2;    // 3200000
    int ND = in_sizes[2];        // 1000

    int NPAD = ((N + 127) / 128) * 128;
    int TILES = NPAD / 128;
    int nb = (N + 511) >> 9;     // 196 buckets
    size_t EST = (size_t)nb * BSTRIDE;

    char* p = (char*)d_ws;
    auto alloc = [&](size_t bytes) {
        char* r = p;
        p += (bytes + 255) & ~(size_t)255;
        return r;
    };
    int*   deg    = (int*)alloc((size_t)NPAD * 4);
    int*   off    = (int*)alloc((size_t)NPAD * 4);
    float* dinv   = (float*)alloc((size_t)NPAD * 4);
    int*   csr    = (int*)alloc(EST * 4);
    float* A      = (float*)alloc((size_t)NPAD * 64 * 4);   // eu alias during build, then H1s
    float* B      = (float*)alloc((size_t)NPAD * 64 * 4);   // agg2
    float* xs     = (float*)alloc((size_t)NPAD * 8 * 4);
    float* dgt    = (float*)alloc((size_t)ND * 64 * 4);
    float* scores = (float*)alloc((size_t)NPAD * 4);
    int*   bcur   = (int*)alloc(256 * 4);
    float* pm     = (float*)alloc(256 * 4);
    float* ps     = (float*)alloc(256 * 4);
    int*   pidx   = (int*)alloc(256 * 4);
    if ((size_t)(p - (char*)d_ws) > ws_size) return;

    unsigned* eu = (unsigned*)A;   // EST*4 = 13.65MB <= 25.6MB; dead before k_c8h1 writes A

    const int* esrc = ei;
    const int* edst = ei + E;

    hipMemsetAsync(bcur, 0, 256 * 4, stream);
    k_bscatter1p<<<(E + CHUNK - 1) / CHUNK, 256, 0, stream>>>(esrc, edst, E, bcur, eu);
    k_bprep<<<nb, 256, 0, stream>>>(eu, bcur, x, deg, off, dinv, xs, csr, N);

    // conv1 gather + W1 GEMM fused
    k_c8h1<<<(N * 8 + 255) / 256, 256, 0, stream>>>(xs, csr, off, deg, W1, b1, dinv, A, N);

    // conv2 gather
    k_conv64<<<(N + 3) / 4, 256, 0, stream>>>(A, csr, off, deg, B, N);

    // dag/global embeddings from agg2, then fused MLP -> scores
    k_dgt2<<<(ND * 64 + 255) / 256, 256, 0, stream>>>(B, dsi, dinv, W2, b2, M1, b1, dgt, N, ND);
    k_gm<<<TILES, 256, 0, stream>>>(B, dinv, W2, b2, dgt, x, M1, M2, mb2, M3, mb3, scores, N, ND);

    int NS = N - 1;
    k_red_ms<<<256, 256, 0, stream>>>(scores, NS, pm, ps, pidx);
    k_probs<<<(NS + 256) / 256, 256, 0, stream>>>(scores, pm, ps, pidx, 256, (float*)d_out, NS);
}

// Round 15
// 286.609 us; speedup vs baseline: 1.0379x; 1.0379x over previous
//
#include <hip/hip_runtime.h>
#include <math.h>

#define CHUNK 8192
#define BSTRIDE 17408   // per-bucket edge capacity: mean 16327 + >8 sigma

// ================= single-pass bucket scatter (packed u32, fixed-stride buckets) =================
// bucket b = dst >> 9 (512 nodes); edge packed as (src << 9) | (dst & 511)

__global__ void __launch_bounds__(256) k_bscatter1p(const int* __restrict__ src,
                                                    const int* __restrict__ dst, int e,
                                                    int* __restrict__ bcur,
                                                    unsigned* __restrict__ eu) {
    __shared__ unsigned short rank[CHUNK];
    __shared__ int cnt[256];
    __shared__ int base[256];
    int t = threadIdx.x;
    int c0 = blockIdx.x * CHUNK;
    cnt[t] = 0;
    __syncthreads();
#pragma unroll
    for (int k = 0; k < CHUNK / 256; k++) {
        int i = c0 + k * 256 + t;
        if (i < e) {
            int b = dst[i] >> 9;
            rank[k * 256 + t] = (unsigned short)atomicAdd(&cnt[b], 1);
        }
    }
    __syncthreads();
    int cb = cnt[t];
    base[t] = cb ? atomicAdd(&bcur[t], cb) : 0;
    __syncthreads();
#pragma unroll
    for (int k = 0; k < CHUNK / 256; k++) {
        int i = c0 + k * 256 + t;
        if (i < e) {
            int d = dst[i];
            int b = d >> 9;
            eu[(size_t)b * BSTRIDE + base[b] + rank[k * 256 + t]] =
                ((unsigned)src[i] << 9) | (unsigned)(d & 511);
        }
    }
}

// per bucket: histogram+scan -> deg/off/dinv, xs = x*dinv, scatter csr (two eu passes, LDS atomics)
__global__ void __launch_bounds__(256) k_bprep(const unsigned* __restrict__ eu,
                                               const int* __restrict__ bcur,
                                               const float* __restrict__ x,
                                               int* __restrict__ deg, int* __restrict__ off,
                                               float* __restrict__ dinv, float* __restrict__ xs,
                                               int* __restrict__ csr, int n) {
    __shared__ int h[512];
    __shared__ int offL[512];
    __shared__ int curL[512];
    __shared__ float sdv[512];
    int t = threadIdx.x, b = blockIdx.x;
    h[t] = 0; h[t + 256] = 0;
    curL[t] = 0; curL[t + 256] = 0;
    __syncthreads();
    int s0 = b * BSTRIDE;
    int s1 = s0 + bcur[b];
    for (int i = s0 + t; i < s1; i += 256)
        atomicAdd(&h[eu[i] & 511u], 1);
    __syncthreads();
    int o0 = h[t], o1 = h[t + 256];
    for (int d = 1; d < 512; d <<= 1) {
        int a0 = (t >= d) ? h[t - d] : 0;
        int a1 = (t + 256 >= d) ? h[t + 256 - d] : 0;
        __syncthreads();
        h[t] += a0; h[t + 256] += a1;
        __syncthreads();
    }
    int nbase = b << 9;
    int n0 = nbase + t, n1 = nbase + t + 256;
    int ofA = s0 + h[t] - o0, ofB = s0 + h[t + 256] - o1;
    offL[t] = ofA; offL[t + 256] = ofB;
    if (n0 < n) {
        float dv = rsqrtf((float)(o0 + 1));
        deg[n0] = o0; off[n0] = ofA; dinv[n0] = dv; sdv[t] = dv;
    }
    if (n1 < n) {
        float dv = rsqrtf((float)(o1 + 1));
        deg[n1] = o1; off[n1] = ofB; dinv[n1] = dv; sdv[t + 256] = dv;
    }
    __syncthreads();
    int limit = (n - nbase) * 8;
    if (limit > 4096) limit = 4096;
    for (int idx = t; idx < limit; idx += 256)
        xs[(size_t)nbase * 8 + idx] = x[(size_t)nbase * 8 + idx] * sdv[idx >> 3];
    for (int i = s0 + t; i < s1; i += 256) {
        unsigned p = eu[i];
        int local = (int)(p & 511u);
        int r = atomicAdd(&curL[local], 1);
        csr[offL[local] + r] = (int)(p >> 9);
    }
}

// ================= conv1 gather + W1 GEMM fused =================

__global__ void __launch_bounds__(256) k_c8h1(const float* __restrict__ xs,
                                              const int* __restrict__ csr,
                                              const int* __restrict__ off,
                                              const int* __restrict__ deg,
                                              const float* __restrict__ W1,
                                              const float* __restrict__ b1,
                                              const float* __restrict__ dinv,
                                              float* __restrict__ H1s, int n) {
    __shared__ float w1s[512];
    __shared__ float b1s[64];
    int t = threadIdx.x;
    w1s[t] = W1[t];
    w1s[t + 256] = W1[t + 256];
    if (t < 64) b1s[t] = b1[t];
    __syncthreads();
    int g = (blockIdx.x * 256 + t) >> 3;
    int lane = t & 7;
    if (g >= n) return;
    int base = off[g], cnt = deg[g];
    float acc = xs[g * 8 + lane];
    int e = 0;
    for (; e + 4 <= cnt; e += 4) {
        int s0 = csr[base + e];
        int s1 = csr[base + e + 1];
        int s2 = csr[base + e + 2];
        int s3 = csr[base + e + 3];
        acc += xs[s0 * 8 + lane];
        acc += xs[s1 * 8 + lane];
        acc += xs[s2 * 8 + lane];
        acc += xs[s3 * 8 + lane];
    }
    for (; e < cnt; e++) acc += xs[csr[base + e] * 8 + lane];
    float dv = dinv[g];
    float o[8];
#pragma unroll
    for (int j = 0; j < 8; j++) o[j] = 0.f;
#pragma unroll
    for (int k = 0; k < 8; k++) {
        float av = __shfl(acc, (t & 56) | k);
#pragma unroll
        for (int j = 0; j < 8; j++) o[j] += av * w1s[k * 64 + lane * 8 + j];
    }
    float4 r0, r1;
    r0.x = fmaxf(dv * o[0] + b1s[lane * 8 + 0], 0.f) * dv;
    r0.y = fmaxf(dv * o[1] + b1s[lane * 8 + 1], 0.f) * dv;
    r0.z = fmaxf(dv * o[2] + b1s[lane * 8 + 2], 0.f) * dv;
    r0.w = fmaxf(dv * o[3] + b1s[lane * 8 + 3], 0.f) * dv;
    r1.x = fmaxf(dv * o[4] + b1s[lane * 8 + 4], 0.f) * dv;
    r1.y = fmaxf(dv * o[5] + b1s[lane * 8 + 5], 0.f) * dv;
    r1.z = fmaxf(dv * o[6] + b1s[lane * 8 + 6], 0.f) * dv;
    r1.w = fmaxf(dv * o[7] + b1s[lane * 8 + 7], 0.f) * dv;
    *(float4*)&H1s[(size_t)g * 64 + lane * 8]     = r0;
    *(float4*)&H1s[(size_t)g * 64 + lane * 8 + 4] = r1;
}

// ================= conv2 aggregate: one wave per dst, 8 rows in flight =================

__global__ void __launch_bounds__(256) k_conv64(const float* __restrict__ G,
                                                const int* __restrict__ csr,
                                                const int* __restrict__ off,
                                                const int* __restrict__ deg,
                                                float* __restrict__ agg2, int n) {
    int d = (blockIdx.x * 256 + threadIdx.x) >> 6;
    int j = threadIdx.x & 63;
    if (d >= n) return;
    int du = __builtin_amdgcn_readfirstlane(d);
    int base = off[du], cnt = deg[du];
    const float* Gj = G + j;
    float acc = Gj[(size_t)du * 64];
    int e = 0;
    for (; e + 8 <= cnt; e += 8) {
        int s[8];
#pragma unroll
        for (int u = 0; u < 8; u++) s[u] = csr[base + e + u];
        float v[8];
#pragma unroll
        for (int u = 0; u < 8; u++) v[u] = Gj[(size_t)s[u] * 64];
#pragma unroll
        for (int u = 0; u < 8; u++) acc += v[u];
    }
    for (; e < cnt; e++) acc += Gj[(size_t)csr[base + e] * 64];
    agg2[(size_t)d * 64 + j] = acc;
}

// ================= dgt[w][j] = b1[j] + Hfin(dsi[w])@M1b + Hfin(n-1)@M1c (from agg2) =================

__global__ void k_dgt2(const float* __restrict__ agg2, const int* __restrict__ dsi,
                       const float* __restrict__ dinv,
                       const float* __restrict__ W2, const float* __restrict__ b2,
                       const float* __restrict__ M1, const float* __restrict__ b1,
                       float* __restrict__ dgt, int n, int nd) {
    int w = (blockIdx.x * blockDim.x + threadIdx.x) >> 6;
    int lane = threadIdx.x & 63;
    if (w >= nd) return;
    int nodeD = dsi[w];
    float avD = agg2[(size_t)nodeD * 64 + lane];
    float dvD = dinv[nodeD];
    float avG = agg2[(size_t)(n - 1) * 64 + lane];
    float dvG = dinv[n - 1];
    float sD = 0.f, sG = 0.f;
#pragma unroll
    for (int k = 0; k < 64; k++) {
        float wv = W2[k * 64 + lane];
        sD += __shfl(avD, k) * wv;
        sG += __shfl(avG, k) * wv;
    }
    float bb = b2[lane];
    float hd = fmaxf(dvD * sD + bb, 0.f);
    float hg = fmaxf(dvG * sG + bb, 0.f);
    float z = b1[lane];
#pragma unroll
    for (int k = 0; k < 64; k++) z += __shfl(hd, k) * M1[(64 + k) * 64 + lane];
#pragma unroll
    for (int k = 0; k < 64; k++) z += __shfl(hg, k) * M1[(128 + k) * 64 + lane];
    dgt[w * 64 + lane] = z;
}

// ================= fused: Hfin=relu(dinv*(agg2@W2)+b2) -> MLP -> scores =================

__global__ void __launch_bounds__(256) k_gm(const float* __restrict__ agg2,
                                            const float* __restrict__ dinv,
                                            const float* __restrict__ W2,
                                            const float* __restrict__ b2,
                                            const float* __restrict__ dgt,
                                            const float* __restrict__ x,
                                            const float* __restrict__ M1,
                                            const float* __restrict__ M2,
                                            const float* __restrict__ mb2,
                                            const float* __restrict__ M3,
                                            const float* __restrict__ mb3,
                                            float* __restrict__ scores, int n, int nd) {
    __shared__ float hs[128 * 65];
    __shared__ float ws[64 * 64];
    int tid = threadIdx.x;
    int base = blockIdx.x * 128;
#pragma unroll
    for (int m = 0; m < 4; m++) {
        int i = (m * 256 + tid) * 4;
        *(float4*)&ws[i] = *(const float4*)&W2[i];
    }
#pragma unroll
    for (int m = 0; m < 8; m++) {
        int idx = (m * 256 + tid) * 4;
        int node = idx >> 6, k = idx & 63;
        float4 v = *(const float4*)&agg2[(size_t)(base + node) * 64 + k];
        hs[node * 65 + k]     = v.x;
        hs[node * 65 + k + 1] = v.y;
        hs[node * 65 + k + 2] = v.z;
        hs[node * 65 + k + 3] = v.w;
    }
    __syncthreads();
    int jg = tid & 7, ng = tid >> 3;
    int j0 = jg * 8, n0 = ng * 4;
    float acc[4][8];
#pragma unroll
    for (int i = 0; i < 4; i++)
#pragma unroll
        for (int j = 0; j < 8; j++) acc[i][j] = 0.f;
#pragma unroll 4
    for (int k = 0; k < 64; k++) {
        float av[4];
#pragma unroll
        for (int i = 0; i < 4; i++) av[i] = hs[(n0 + i) * 65 + k];
        float bv[8];
        *(float4*)&bv[0] = *(float4*)&ws[k * 64 + j0];
        *(float4*)&bv[4] = *(float4*)&ws[k * 64 + j0 + 4];
#pragma unroll
        for (int i = 0; i < 4; i++)
#pragma unroll
            for (int j = 0; j < 8; j++) acc[i][j] += av[i] * bv[j];
    }
    __syncthreads();
    float b2v[8];
    *(float4*)&b2v[0] = *(const float4*)&b2[j0];
    *(float4*)&b2v[4] = *(const float4*)&b2[j0 + 4];
#pragma unroll
    for (int i = 0; i < 4; i++) {
        int node = base + n0 + i;
        float dv = (node < n) ? dinv[node] : 0.f;
#pragma unroll
        for (int j = 0; j < 8; j++)
            hs[(n0 + i) * 65 + j0 + j] = fmaxf(acc[i][j] * dv + b2v[j], 0.f);
    }
#pragma unroll
    for (int m = 0; m < 4; m++) {
        int i = (m * 256 + tid) * 4;
        *(float4*)&ws[i] = *(const float4*)&M1[i];
    }
    __syncthreads();
#pragma unroll
    for (int i = 0; i < 4; i++)
#pragma unroll
        for (int j = 0; j < 8; j++) acc[i][j] = 0.f;
#pragma unroll 4
    for (int k = 0; k < 64; k++) {
        float av[4];
#pragma unroll
        for (int i = 0; i < 4; i++) av[i] = hs[(n0 + i) * 65 + k];
        float bv[8];
        *(float4*)&bv[0] = *(float4*)&ws[k * 64 + j0];
        *(float4*)&bv[4] = *(float4*)&ws[k * 64 + j0 + 4];
#pragma unroll
        for (int i = 0; i < 4; i++)
#pragma unroll
            for (int j = 0; j < 8; j++) acc[i][j] += av[i] * bv[j];
    }
    __syncthreads();
#pragma unroll
    for (int i = 0; i < 4; i++) {
        int node = base + n0 + i;
        int dago = (node + 1) / 100;
        if (dago >= nd) dago = nd - 1;
        float dv[8];
        *(float4*)&dv[0] = *(const float4*)&dgt[dago * 64 + j0];
        *(float4*)&dv[4] = *(const float4*)&dgt[dago * 64 + j0 + 4];
#pragma unroll
        for (int j = 0; j < 8; j++)
            hs[(n0 + i) * 65 + j0 + j] = fmaxf(acc[i][j] + dv[j], 0.f);
    }
#pragma unroll
    for (int m = 0; m < 4; m++) {
        int i = (m * 256 + tid) * 4;
        *(float4*)&ws[i] = *(const float4*)&M2[i];
    }
    __syncthreads();
    float acc2[4][8];
#pragma unroll
    for (int i = 0; i < 4; i++)
#pragma unroll
        for (int j = 0; j < 8; j++) acc2[i][j] = 0.f;
#pragma unroll 4
    for (int k = 0; k < 64; k++) {
        float av[4];
#pragma unroll
        for (int i = 0; i < 4; i++) av[i] = hs[(n0 + i) * 65 + k];
        float bv[8];
        *(float4*)&bv[0] = *(float4*)&ws[k * 64 + j0];
        *(float4*)&bv[4] = *(float4*)&ws[k * 64 + j0 + 4];
#pragma unroll
        for (int i = 0; i < 4; i++)
#pragma unroll
            for (int j = 0; j < 8; j++) acc2[i][j] += av[i] * bv[j];
    }
    float mb2v[8], m3v[8];
    *(float4*)&mb2v[0] = *(const float4*)&mb2[j0];
    *(float4*)&mb2v[4] = *(const float4*)&mb2[j0 + 4];
    *(float4*)&m3v[0] = *(const float4*)&M3[j0];
    *(float4*)&m3v[4] = *(const float4*)&M3[j0 + 4];
    float b3 = mb3[0];
#pragma unroll
    for (int i = 0; i < 4; i++) {
        float p = 0.f;
#pragma unroll
        for (int j = 0; j < 8; j++) {
            float z2 = fmaxf(acc2[i][j] + mb2v[j], 0.f);
            p += z2 * m3v[j];
        }
        p += __shfl_xor(p, 1);
        p += __shfl_xor(p, 2);
        p += __shfl_xor(p, 4);
        if (jg == 0) {
            int node = base + n0 + i;
            if (node < n - 1) {
                float flag = x[(size_t)node * 8 + 7];
                bool summary = ((node % 100) == 99);
                scores[node] = (flag == 1.0f && !summary) ? (p + b3) : -INFINITY;
            }
        }
    }
}

// ================= fused online max/argmax/exp-sum reduction =================

__global__ void k_red_ms(const float* __restrict__ scores, int n,
                         float* __restrict__ pm, float* __restrict__ ps,
                         int* __restrict__ pidx) {
    __shared__ float sm[256];
    __shared__ float ss[256];
    __shared__ int si[256];
    float m = -INFINITY, s = 0.f;
    int bi = 0x7fffffff;
    for (int i = blockIdx.x * 256 + threadIdx.x; i < n; i += gridDim.x * 256) {
        float v = scores[i];
        if (v > m) {
            s = s * expf(m - v) + 1.f;
            m = v;
            bi = i;
        } else if (v != -INFINITY) {
            s += expf(v - m);
        }
    }
    sm[threadIdx.x] = m; ss[threadIdx.x] = s; si[threadIdx.x] = bi;
    __syncthreads();
    for (int o = 128; o; o >>= 1) {
        if (threadIdx.x < o) {
            float m2 = sm[threadIdx.x + o], s2 = ss[threadIdx.x + o];
            int i2 = si[threadIdx.x + o];
            float m1 = sm[threadIdx.x], s1 = ss[threadIdx.x];
            int i1 = si[threadIdx.x];
            float M = fmaxf(m1, m2);
            float S = ((m1 == -INFINITY) ? 0.f : s1 * expf(m1 - M)) +
                      ((m2 == -INFINITY) ? 0.f : s2 * expf(m2 - M));
            int I;
            if (m2 > m1 || (m2 == m1 && i2 < i1)) I = i2; else I = i1;
            sm[threadIdx.x] = M; ss[threadIdx.x] = S; si[threadIdx.x] = I;
        }
        __syncthreads();
    }
    if (threadIdx.x == 0) { pm[blockIdx.x] = sm[0]; ps[blockIdx.x] = ss[0]; pidx[blockIdx.x] = si[0]; }
}

// combine (replicated per block, deterministic) + write probs
__global__ void k_probs(const float* __restrict__ scores,
                        const float* __restrict__ pm, const float* __restrict__ ps,
                        const int* __restrict__ pidx, int nb,
                        float* __restrict__ out, int n) {
    __shared__ float sm[256];
    __shared__ float ss[256];
    __shared__ int si[256];
    int t = threadIdx.x;
    sm[t] = (t < nb) ? pm[t] : -INFINITY;
    ss[t] = (t < nb) ? ps[t] : 0.f;
    si[t] = (t < nb) ? pidx[t] : 0x7fffffff;
    __syncthreads();
    for (int o = 128; o; o >>= 1) {
        if (t < o) {
            float m2 = sm[t + o], s2 = ss[t + o];
            int i2 = si[t + o];
            float m1 = sm[t], s1 = ss[t];
            int i1 = si[t];
            float M = fmaxf(m1, m2);
            float S = ((m1 == -INFINITY) ? 0.f : s1 * expf(m1 - M)) +
                      ((m2 == -INFINITY) ? 0.f : s2 * expf(m2 - M));
            int I;
            if (m2 > m1 || (m2 == m1 && i2 < i1)) I = i2; else I = i1;
            sm[t] = M; ss[t] = S; si[t] = I;
        }
        __syncthreads();
    }
    float m = sm[0], s = ss[0];
    int i = blockIdx.x * 256 + t;
    if (i < n) out[i] = expf(scores[i] - m) / s;
    if (i == 0) out[n] = (float)si[0];
}

// ================= host =================

extern "C" void kernel_launch(void* const* d_in, const int* in_sizes, int n_in,
                              void* d_out, int out_size, void* d_ws, size_t ws_size,
                              hipStream_t stream) {
    const float* x   = (const float*)d_in[0];
    const int*   ei  = (const int*)d_in[1];
    const int*   dsi = (const int*)d_in[2];
    const float* W1  = (const float*)d_in[3];
    const float* b1  = (const float*)d_in[4];
    const float* W2  = (const float*)d_in[5];
    const float* b2  = (const float*)d_in[6];
    const float* M1  = (const float*)d_in[7];
    const float* mb1 = (const float*)d_in[8];  (void)mb1;
    const float* M2  = (const float*)d_in[9];
    const float* mb2 = (const float*)d_in[10];
    const float* M3  = (const float*)d_in[11];
    const float* mb3 = (const float*)d_in[12];

    int N  = in_sizes[0] / 8;    // 100001
    int E  = in_sizes[1] / 2;    // 3200000
    int ND = in_sizes[2];        // 1000

    int NPAD = ((N + 127) / 128) * 128;
    int TILES = NPAD / 128;
    int nb = (N + 511) >> 9;     // 196 buckets
    size_t EST = (size_t)nb * BSTRIDE;

    char* p = (char*)d_ws;
    auto alloc = [&](size_t bytes) {
        char* r = p;
        p += (bytes + 255) & ~(size_t)255;
        return r;
    };
    int*   deg    = (int*)alloc((size_t)NPAD * 4);
    int*   off    = (int*)alloc((size_t)NPAD * 4);
    float* dinv   = (float*)alloc((size_t)NPAD * 4);
    int*   csr    = (int*)alloc(EST * 4);
    float* A      = (float*)alloc((size_t)NPAD * 64 * 4);   // eu alias during build, then H1s
    float* B      = (float*)alloc((size_t)NPAD * 64 * 4);   // agg2
    float* xs     = (float*)alloc((size_t)NPAD * 8 * 4);
    float* dgt    = (float*)alloc((size_t)ND * 64 * 4);
    float* scores = (float*)alloc((size_t)NPAD * 4);
    int*   bcur   = (int*)alloc(256 * 4);
    float* pm     = (float*)alloc(256 * 4);
    float* ps     = (float*)alloc(256 * 4);
    int*   pidx   = (int*)alloc(256 * 4);
    if ((size_t)(p - (char*)d_ws) > ws_size) return;

    unsigned* eu = (unsigned*)A;   // EST*4 = 13.65MB <= 25.6MB; dead before k_c8h1 writes A

    const int* esrc = ei;
    const int* edst = ei + E;

    hipMemsetAsync(bcur, 0, 256 * 4, stream);
    k_bscatter1p<<<(E + CHUNK - 1) / CHUNK, 256, 0, stream>>>(esrc, edst, E, bcur, eu);
    k_bprep<<<nb, 256, 0, stream>>>(eu, bcur, x, deg, off, dinv, xs, csr, N);

    // conv1 gather + W1 GEMM fused
    k_c8h1<<<(N * 8 + 255) / 256, 256, 0, stream>>>(xs, csr, off, deg, W1, b1, dinv, A, N);

    // conv2 gather
    k_conv64<<<(N + 3) / 4, 256, 0, stream>>>(A, csr, off, deg, B, N);

    // dag/global embeddings from agg2, then fused MLP -> scores
    k_dgt2<<<(ND * 64 + 255) / 256, 256, 0, stream>>>(B, dsi, dinv, W2, b2, M1, b1, dgt, N, ND);
    k_gm<<<TILES, 256, 0, stream>>>(B, dinv, W2, b2, dgt, x, M1, M2, mb2, M3, mb3, scores, N, ND);

    int NS = N - 1;
    k_red_ms<<<256, 256, 0, stream>>>(scores, NS, pm, ps, pidx);
    k_probs<<<(NS + 256) / 256, 256, 0, stream>>>(scores, pm, ps, pidx, 256, (float*)d_out, NS);
}